// Round 7
// baseline (1599.696 us; speedup 1.0000x reference)
//
#include <hip/hip_runtime.h>

#define NN    50000
#define EE    800000
#define DIN   512
#define DH    128
#define NC    64
#define KITER 10
#define NSB   196          // ceil(NN/256) scan blocks; also v-step blocks
#define XSLB  6256         // x-step blocks: 8 slices * 782 node-chunks

typedef __attribute__((ext_vector_type(8))) short short8;
typedef __attribute__((ext_vector_type(4))) short short4v;
typedef __attribute__((ext_vector_type(4))) float f32x4;
typedef unsigned long long ull;

static __device__ __forceinline__ float bf2f(short u) {
  unsigned int x = ((unsigned int)(unsigned short)u) << 16;
  return __builtin_bit_cast(float, x);
}
static __device__ __forceinline__ short f2bf(float f) {
  unsigned int x = __builtin_bit_cast(unsigned int, f);
  unsigned int lsb = (x >> 16) & 1u;
  x += 0x7fffu + lsb;                    // round-to-nearest-even
  return (short)(x >> 16);
}

// ---- fused: X -> out0 (byte exact) AND X -> bf16 Xb (in d_ws) --------------
__global__ void k_copy_conv(const f32x4* __restrict__ src, f32x4* __restrict__ dst,
                            short4v* __restrict__ xb) {
  int i = blockIdx.x * 256 + threadIdx.x;       // 6.4M f32x4 exact
  f32x4 s = src[i];
  dst[i] = s;
  short4v o = { f2bf(s.x), f2bf(s.y), f2bf(s.z), f2bf(s.w) };
  xb[i] = o;
}

// ---- fallback pieces (used only if d_ws too small) -------------------------
__global__ void k_copy4(const f32x4* __restrict__ src, f32x4* __restrict__ dst) {
  int i = blockIdx.x * 256 + threadIdx.x;
  dst[i] = src[i];
}

__global__ void k_f2bv(const float* __restrict__ src, short* __restrict__ dst) {
  int j = (blockIdx.x * 256 + threadIdx.x) * 4;
  f32x4 s = *(const f32x4*)(src + j);
  short4v o = { f2bf(s.x), f2bf(s.y), f2bf(s.z), f2bf(s.w) };
  *(short4v*)(dst + j) = o;
}

// ---- CSR build -------------------------------------------------------------
__global__ void k_count(const int* __restrict__ ei, int* __restrict__ cnt) {
  int e = blockIdx.x * 256 + threadIdx.x;
  if (e < EE) atomicAdd(&cnt[ei[EE + e]], 1);
}

// phase 1: per-block inclusive scan + dinv (fused)
__global__ __launch_bounds__(256) void k_scan1(const int* __restrict__ cnt,
                                               int* __restrict__ rp,
                                               int* __restrict__ bsum,
                                               float* __restrict__ dinv) {
  __shared__ int wsum[4];
  int t = threadIdx.x, lane = t & 63, w = t >> 6;
  int i = blockIdx.x * 256 + t;
  int x = (i < NN) ? cnt[i] : 0;
  if (i < NN) dinv[i] = rsqrtf((float)(x + 1));   // +1 self-loop
  #pragma unroll
  for (int off = 1; off < 64; off <<= 1) {
    int y = __shfl_up(x, off);
    if (lane >= off) x += y;
  }
  if (lane == 63) wsum[w] = x;
  __syncthreads();
  int woff = 0;
  #pragma unroll
  for (int j = 0; j < 4; ++j) if (j < w) woff += wsum[j];
  x += woff;
  if (i < NN) rp[i + 1] = x;
  if (t == 255) bsum[blockIdx.x] = x;   // block inclusive total (pad is 0)
}

// phase 2: exclusive scan of the 196 block totals, in place (single block)
__global__ __launch_bounds__(256) void k_scan2(int* __restrict__ bsum) {
  __shared__ int wsum[4];
  int t = threadIdx.x, lane = t & 63, w = t >> 6;
  int orig = (t < NSB) ? bsum[t] : 0;
  int x = orig;
  #pragma unroll
  for (int off = 1; off < 64; off <<= 1) {
    int y = __shfl_up(x, off);
    if (lane >= off) x += y;
  }
  if (lane == 63) wsum[w] = x;
  __syncthreads();
  int woff = 0;
  #pragma unroll
  for (int j = 0; j < 4; ++j) if (j < w) woff += wsum[j];
  x += woff;
  if (t < NSB) bsum[t] = x - orig;      // exclusive prefix
}

// phase 3: add block offsets; rp[0] = 0
__global__ __launch_bounds__(256) void k_scan3(int* __restrict__ rp,
                                               const int* __restrict__ bsum) {
  int i = blockIdx.x * 256 + threadIdx.x;
  if (i == 0) rp[0] = 0;
  if (i < NN) rp[i + 1] += bsum[blockIdx.x];
}

// fill packed edge array: ev[idx] = (f32bits(val)<<32) | col  (one 8B store
// per edge instead of two scattered 4B stores; nt keeps it out of L2)
__global__ void k_fill(const int* __restrict__ ei, const int* __restrict__ rp,
                       int* __restrict__ fill, const float* __restrict__ dinv,
                       ull* __restrict__ ev) {
  int e = blockIdx.x * 256 + threadIdx.x;
  if (e < EE) {
    int s = ei[e], d = ei[EE + e];
    int pos = atomicAdd(&fill[d], 1);
    int idx = rp[d] + pos;
    float v = dinv[s] * dinv[d];
    ull p = ((ull)__builtin_bit_cast(unsigned int, v) << 32) | (unsigned int)s;
    __builtin_nontemporal_store(p, &ev[idx]);
  }
}

// ---- GEMM1: h1 = relu(Xb @ W1b^T + b1), written in SLICED layout -----------
// sliced layout: buf[slice][node][16], slice = n>>4 (== nt), within = n&15 (== r)
__global__ __launch_bounds__(256) void k_gemm1(const short* __restrict__ Xb,
                                               const short* __restrict__ W1b,
                                               const float* __restrict__ B1,
                                               short* __restrict__ h1s,
                                               float* __restrict__ st0) {
  int w = threadIdx.x >> 6;
  int lane = threadIdx.x & 63;
  int q = lane >> 4, r = lane & 15;
  int m0 = blockIdx.x * 64 + w * 16;

  f32x4 acc[8];
  #pragma unroll
  for (int i = 0; i < 8; ++i) acc[i] = (f32x4){0.f, 0.f, 0.f, 0.f};

  int row_a = m0 + r;
  if (row_a >= NN) row_a = NN - 1;            // clamp loads, stores masked
  const short* xrow = Xb + (size_t)row_a * DIN + q * 8;

  for (int kc = 0; kc < DIN / 32; ++kc) {
    short8 a = *(const short8*)(xrow + kc * 32);
    #pragma unroll
    for (int nt = 0; nt < 8; ++nt) {
      const short* wrow = W1b + (size_t)(nt * 16 + r) * DIN + q * 8 + kc * 32;
      short8 b = *(const short8*)wrow;
      acc[nt] = __builtin_amdgcn_mfma_f32_16x16x32_bf16(a, b, acc[nt], 0, 0, 0);
    }
  }

  #pragma unroll
  for (int nt = 0; nt < 8; ++nt) {
    float bias = B1[nt * 16 + r];
    #pragma unroll
    for (int reg = 0; reg < 4; ++reg) {
      int row = m0 + q * 4 + reg;             // C/D: row = quad*4 + reg
      if (row < NN) {
        float v = acc[nt][reg] + bias;
        v = v > 0.f ? v : 0.f;
        size_t sidx = (size_t)nt * NN * 16 + (size_t)row * 16 + r;
        h1s[sidx] = f2bf(v);
        st0[sidx] = v;
      }
    }
  }
}

// ---- one APPNP step, x-diffusion + v-diffusion merged into one launch ------
// Sliced state st[slice][node][16], slice = bid&7 -> XCD (round-robin).
// CACHE POLICY (the round-7 change): per-XCD L2 should hold ONLY the 3.2MB
// read-state slice. Everything with no intra-step reuse is non-temporal:
//   nt loads:  ev (packed col/val, streamed), h1 (streamed)
//   nt stores: xn (next step's buffer; write-allocate was evicting the
//              current read set -> rounds 3 and 6 both L3-bound at ~60us)
// Normal loads: xc gathers (the 51MB/XCD re-read set we want L2-resident).
__global__ __launch_bounds__(256) void k_step(const int* __restrict__ rp,
                                              const ull* __restrict__ ev,
                                              const float* __restrict__ dinv,
                                              const float* __restrict__ xc,
                                              const short* __restrict__ h0,
                                              float* __restrict__ xn,
                                              const float* __restrict__ vc,
                                              float* __restrict__ vn,
                                              int first, int last) {
  if (blockIdx.x >= XSLB) {                   // ---- v-step tail blocks ----
    int i = (blockIdx.x - XSLB) * 256 + threadIdx.x;
    if (i >= NN) return;
    float s = 0.f;
    int e = rp[i], end = rp[i + 1];
    if (first) {                              // vc == 1.0 exactly
      for (; e + 4 <= end; e += 4) {
        ull p0 = __builtin_nontemporal_load(ev + e);
        ull p1 = __builtin_nontemporal_load(ev + e + 1);
        ull p2 = __builtin_nontemporal_load(ev + e + 2);
        ull p3 = __builtin_nontemporal_load(ev + e + 3);
        s += __builtin_bit_cast(float, (unsigned int)(p0 >> 32));
        s += __builtin_bit_cast(float, (unsigned int)(p1 >> 32));
        s += __builtin_bit_cast(float, (unsigned int)(p2 >> 32));
        s += __builtin_bit_cast(float, (unsigned int)(p3 >> 32));
      }
      for (; e < end; ++e) {
        ull p = __builtin_nontemporal_load(ev + e);
        s += __builtin_bit_cast(float, (unsigned int)(p >> 32));
      }
      float di = dinv[i];
      s += di * di;
    } else {
      for (; e + 4 <= end; e += 4) {
        ull p0 = __builtin_nontemporal_load(ev + e);
        ull p1 = __builtin_nontemporal_load(ev + e + 1);
        ull p2 = __builtin_nontemporal_load(ev + e + 2);
        ull p3 = __builtin_nontemporal_load(ev + e + 3);
        float v0 = __builtin_bit_cast(float, (unsigned int)(p0 >> 32)) * vc[(unsigned int)p0 & 0xffffffffu];
        float v1 = __builtin_bit_cast(float, (unsigned int)(p1 >> 32)) * vc[(unsigned int)p1 & 0xffffffffu];
        float v2 = __builtin_bit_cast(float, (unsigned int)(p2 >> 32)) * vc[(unsigned int)p2 & 0xffffffffu];
        float v3 = __builtin_bit_cast(float, (unsigned int)(p3 >> 32)) * vc[(unsigned int)p3 & 0xffffffffu];
        s += v0; s += v1; s += v2; s += v3;
      }
      for (; e < end; ++e) {
        ull p = __builtin_nontemporal_load(ev + e);
        s += __builtin_bit_cast(float, (unsigned int)(p >> 32)) * vc[(unsigned int)p & 0xffffffffu];
      }
      float di = dinv[i];
      s += di * di * vc[i];
    }
    vn[i] = 0.9f * s + 0.1f;
    return;
  }
  // ---- x-step: slice sl for 64 nodes, 4 lanes/node, f32x4/lane ----
  int sl = blockIdx.x & 7;                    // slice -> XCD (round-robin)
  int ck = blockIdx.x >> 3;                   // node chunk
  int node = ck * 64 + (threadIdx.x >> 2);
  if (node >= NN) return;
  int fo = (threadIdx.x & 3) * 4;             // f32 offset within 16-f32 slice
  const float* xsl = xc + (size_t)sl * NN * 16;   // this slice's state base
  int e = rp[node], end = rp[node + 1];
  // hoist independent self-loop + h0 loads off the critical path
  f32x4 xself = *(const f32x4*)(xsl + (size_t)node * 16 + fo);
  ull hq = __builtin_nontemporal_load(
      (const ull*)(h0 + (size_t)sl * NN * 16 + (size_t)node * 16 + fo));
  float di = dinv[node];
  f32x4 acc = (f32x4){0.f, 0.f, 0.f, 0.f};
  for (; e + 4 <= end; e += 4) {
    ull p0 = __builtin_nontemporal_load(ev + e);
    ull p1 = __builtin_nontemporal_load(ev + e + 1);
    ull p2 = __builtin_nontemporal_load(ev + e + 2);
    ull p3 = __builtin_nontemporal_load(ev + e + 3);
    int s0 = (int)((unsigned int)p0); float w0 = __builtin_bit_cast(float, (unsigned int)(p0 >> 32));
    int s1 = (int)((unsigned int)p1); float w1 = __builtin_bit_cast(float, (unsigned int)(p1 >> 32));
    int s2 = (int)((unsigned int)p2); float w2 = __builtin_bit_cast(float, (unsigned int)(p2 >> 32));
    int s3 = (int)((unsigned int)p3); float w3 = __builtin_bit_cast(float, (unsigned int)(p3 >> 32));
    f32x4 x0 = *(const f32x4*)(xsl + (size_t)s0 * 16 + fo);
    f32x4 x1 = *(const f32x4*)(xsl + (size_t)s1 * 16 + fo);
    f32x4 x2 = *(const f32x4*)(xsl + (size_t)s2 * 16 + fo);
    f32x4 x3 = *(const f32x4*)(xsl + (size_t)s3 * 16 + fo);
    acc += x0 * w0;                           // sequential: same FP order as
    acc += x1 * w1;                           // the serial loop
    acc += x2 * w2;
    acc += x3 * w3;
  }
  for (; e < end; ++e) {
    ull p = __builtin_nontemporal_load(ev + e);
    int s = (int)((unsigned int)p);
    float w = __builtin_bit_cast(float, (unsigned int)(p >> 32));
    acc += *(const f32x4*)(xsl + (size_t)s * 16 + fo) * w;
  }
  acc += xself * (di * di);                   // self-loop (original position)
  f32x4 h = { bf2f((short)hq), bf2f((short)(hq >> 16)),
              bf2f((short)(hq >> 32)), bf2f((short)(hq >> 48)) };
  f32x4 res = acc * 0.9f + h * 0.1f;
  if (last) {                                 // out1 is row-major [node][128]
    __builtin_nontemporal_store(res, (f32x4*)(xn + (size_t)node * DH + sl * 16 + fo));
  } else {
    __builtin_nontemporal_store(res, (f32x4*)(xn + (size_t)sl * NN * 16 + (size_t)node * 16 + fo));
  }
}

// ---- GEMM2: out2 = emb1 @ W2^T + v*b2, all f32 -----------------------------
__global__ __launch_bounds__(256) void k_gemm2(const float* __restrict__ emb,
                                               const float* __restrict__ W2,
                                               const float* __restrict__ B2,
                                               const float* __restrict__ v,
                                               float* __restrict__ out2) {
  __shared__ float sW[NC][DH + 1];
  __shared__ float sb[NC];
  __shared__ float sE[32][DH + 1];
  int t = threadIdx.x;
  for (int i = t; i < NC * DH; i += 256) sW[i / DH][i % DH] = W2[i];
  if (t < NC) sb[t] = B2[t];
  int n0 = blockIdx.x * 32;
  for (int i = t; i < 32 * DH; i += 256) {
    int nl = i / DH, kk = i % DH;
    int node = n0 + nl;
    sE[nl][kk] = (node < NN) ? emb[(size_t)node * DH + kk] : 0.f;
  }
  __syncthreads();
  int nl = t >> 3, cb = t & 7;
  int node = n0 + nl;
  if (node >= NN) return;
  float vn = v[node];
  #pragma unroll
  for (int j = 0; j < 8; ++j) {
    int c = cb + 8 * j;
    float s = 0.f;
    #pragma unroll 4
    for (int k = 0; k < DH; ++k) s += sE[nl][k] * sW[c][k];
    s += vn * sb[c];
    out2[(size_t)node * NC + c] = s;
  }
}

extern "C" void kernel_launch(void* const* d_in, const int* in_sizes, int n_in,
                              void* d_out, int out_size, void* d_ws, size_t ws_size,
                              hipStream_t stream) {
  const float* X  = (const float*)d_in[0];   // [50000,512] f32 (102.4MB)
  const int*   EI = (const int*)d_in[1];     // [2,800000] int32
  const float* W1 = (const float*)d_in[2];   // [128,512] f32
  const float* B1 = (const float*)d_in[3];   // [128] f32
  const float* W2 = (const float*)d_in[4];   // [64,128] f32
  const float* B2 = (const float*)d_in[5];   // [64] f32

  // ---- d_out: 35.2M f32 = 140.8MB ----
  float* out0 = (float*)d_out;                    // [0, 102.4MB): x passthrough
  float* out1 = (float*)d_out + 25600000;         // [102.4, 128MB): emb1
  float* out2 = (float*)d_out + 32000000;         // [128, 140.8MB): out

  // ---- scratch in d_in[0]'s 102.4MB region (X consumed first) + d_ws ------
  char* xr = (char*)d_in[0];
  const size_t XB_BYTES = (size_t)NN * DIN * sizeof(short);  // 51.2MB
  bool use_ws = (d_ws != nullptr) && (ws_size >= XB_BYTES);

  float* bufB = (float*)(xr);                 // [0, 25.6MB) f32 (sliced state)
  short* Xb   = use_ws ? (short*)d_ws : (short*)(xr);  // bf16 gemm1 input
  float* bufA = (float*)(xr + 51200000);      // [51.2, 76.8MB) f32 (sliced)
  short* h1   = (short*)(xr + 76800000);      // [76.8, 89.6MB) bf16 (sliced)
  ull*   ev   = (ull*)  (xr + 89600000);      // packed col|val, 6.4MB -> 96MB
  int*   rp   = (int*)  (xr + 96000000);      // 200,004B
  int*   cnt  = (int*)  (xr + 96200192);      // 200,000B
  int*   fill = (int*)  (xr + 96400192);      // 200,000B
  float* dinv = (float*)(xr + 96600192);      // 200,000B
  float* va   = (float*)(xr + 96800192);
  float* vb   = (float*)(xr + 97000192);
  short* W1b  = (short*)(xr + 97200192);      // 128KB
  int*   bsum = (int*)  (xr + 97400192);      // 784B scan block sums

  // X passthrough + bf16 conversion
  if (use_ws) {
    k_copy_conv<<<dim3(25000), dim3(256), 0, stream>>>(
        (const f32x4*)X, (f32x4*)out0, (short4v*)Xb);
  } else {
    k_copy4<<<dim3(25000), dim3(256), 0, stream>>>((const f32x4*)X, (f32x4*)out0);
    k_f2bv <<<dim3(25000), dim3(256), 0, stream>>>(out0, Xb);
  }
  k_f2bv <<<dim3(64), dim3(256), 0, stream>>>(W1, W1b);   // W1 -> bf16

  hipMemsetAsync(cnt, 0, 400000, stream);     // cnt + fill (contiguous)
  k_count<<<dim3(3125), dim3(256), 0, stream>>>(EI, cnt);
  k_scan1<<<dim3(NSB), dim3(256), 0, stream>>>(cnt, rp, bsum, dinv);
  k_scan2<<<dim3(1),   dim3(256), 0, stream>>>(bsum);
  k_scan3<<<dim3(NSB), dim3(256), 0, stream>>>(rp, bsum);
  k_fill <<<dim3(3125), dim3(256), 0, stream>>>(EI, rp, fill, dinv, ev);

  // h1 (bf16, sliced) + state init (f32, sliced, exact pre-rounding values)
  k_gemm1<<<dim3(782), dim3(256), 0, stream>>>(Xb, W1b, B1, h1, bufA);

  // 10 merged x+v steps; x: A->B, B->A, ... last writes out1 row-major
  for (int it = 0; it < KITER; ++it) {
    const float* xc = (it & 1) ? bufB : bufA;
    float*       xn = (it == KITER - 1) ? out1 : ((it & 1) ? bufA : bufB);
    const float* vcp = (it & 1) ? vb : va;
    float*       vnp = (it & 1) ? va : vb;
    k_step<<<dim3(XSLB + NSB), dim3(256), 0, stream>>>(
        rp, ev, dinv, xc, h1, xn, vcp, vnp,
        it == 0 ? 1 : 0, it == KITER - 1 ? 1 : 0);
  }
  // v ends in va (it=9 writes va); emb1 in out1 (row-major)

  // out2 = emb1 @ W2^T + APPNP(1)*b2   (all f32)
  k_gemm2<<<dim3(1563), dim3(256), 0, stream>>>(out1, W2, B2, va, out2);
}

// Round 8
// 1261.552 us; speedup vs baseline: 1.2680x; 1.2680x over previous
//
#include <hip/hip_runtime.h>

#define NN    50000
#define EE    800000
#define DIN   512
#define DH    128
#define NC    64
#define KITER 10
#define NSB   196          // ceil(NN/256) scan blocks; also v-step blocks
#define XSLB  6256         // x-step blocks: 8 slices * 782 node-chunks

typedef __attribute__((ext_vector_type(8))) short short8;
typedef __attribute__((ext_vector_type(4))) short short4v;
typedef __attribute__((ext_vector_type(4))) float f32x4;
typedef unsigned long long ull;

static __device__ __forceinline__ float bf2f(short u) {
  unsigned int x = ((unsigned int)(unsigned short)u) << 16;
  return __builtin_bit_cast(float, x);
}
static __device__ __forceinline__ short f2bf(float f) {
  unsigned int x = __builtin_bit_cast(unsigned int, f);
  unsigned int lsb = (x >> 16) & 1u;
  x += 0x7fffu + lsb;                    // round-to-nearest-even
  return (short)(x >> 16);
}

// ---- fused: X -> out0 (byte exact) AND X -> bf16 Xb (in d_ws) --------------
__global__ void k_copy_conv(const f32x4* __restrict__ src, f32x4* __restrict__ dst,
                            short4v* __restrict__ xb) {
  int i = blockIdx.x * 256 + threadIdx.x;       // 6.4M f32x4 exact
  f32x4 s = src[i];
  dst[i] = s;
  short4v o = { f2bf(s.x), f2bf(s.y), f2bf(s.z), f2bf(s.w) };
  xb[i] = o;
}

// ---- fallback pieces (used only if d_ws too small) -------------------------
__global__ void k_copy4(const f32x4* __restrict__ src, f32x4* __restrict__ dst) {
  int i = blockIdx.x * 256 + threadIdx.x;
  dst[i] = src[i];
}

__global__ void k_f2bv(const float* __restrict__ src, short* __restrict__ dst) {
  int j = (blockIdx.x * 256 + threadIdx.x) * 4;
  f32x4 s = *(const f32x4*)(src + j);
  short4v o = { f2bf(s.x), f2bf(s.y), f2bf(s.z), f2bf(s.w) };
  *(short4v*)(dst + j) = o;
}

// ---- CSR build -------------------------------------------------------------
__global__ void k_count(const int* __restrict__ ei, int* __restrict__ cnt) {
  int e = blockIdx.x * 256 + threadIdx.x;
  if (e < EE) atomicAdd(&cnt[ei[EE + e]], 1);
}

// phase 1: per-block inclusive scan + dinv (fused)
__global__ __launch_bounds__(256) void k_scan1(const int* __restrict__ cnt,
                                               int* __restrict__ rp,
                                               int* __restrict__ bsum,
                                               float* __restrict__ dinv) {
  __shared__ int wsum[4];
  int t = threadIdx.x, lane = t & 63, w = t >> 6;
  int i = blockIdx.x * 256 + t;
  int x = (i < NN) ? cnt[i] : 0;
  if (i < NN) dinv[i] = rsqrtf((float)(x + 1));   // +1 self-loop
  #pragma unroll
  for (int off = 1; off < 64; off <<= 1) {
    int y = __shfl_up(x, off);
    if (lane >= off) x += y;
  }
  if (lane == 63) wsum[w] = x;
  __syncthreads();
  int woff = 0;
  #pragma unroll
  for (int j = 0; j < 4; ++j) if (j < w) woff += wsum[j];
  x += woff;
  if (i < NN) rp[i + 1] = x;
  if (t == 255) bsum[blockIdx.x] = x;   // block inclusive total (pad is 0)
}

// phase 2: exclusive scan of the 196 block totals, in place (single block)
__global__ __launch_bounds__(256) void k_scan2(int* __restrict__ bsum) {
  __shared__ int wsum[4];
  int t = threadIdx.x, lane = t & 63, w = t >> 6;
  int orig = (t < NSB) ? bsum[t] : 0;
  int x = orig;
  #pragma unroll
  for (int off = 1; off < 64; off <<= 1) {
    int y = __shfl_up(x, off);
    if (lane >= off) x += y;
  }
  if (lane == 63) wsum[w] = x;
  __syncthreads();
  int woff = 0;
  #pragma unroll
  for (int j = 0; j < 4; ++j) if (j < w) woff += wsum[j];
  x += woff;
  if (t < NSB) bsum[t] = x - orig;      // exclusive prefix
}

// phase 3: add block offsets; rp[0] = 0
__global__ __launch_bounds__(256) void k_scan3(int* __restrict__ rp,
                                               const int* __restrict__ bsum) {
  int i = blockIdx.x * 256 + threadIdx.x;
  if (i == 0) rp[0] = 0;
  if (i < NN) rp[i + 1] += bsum[blockIdx.x];
}

// fill CSR col only; val is recomputed in k_step as dinv[s]*dinv[d]
// (bit-exact: same operands, same single multiply)
__global__ void k_fill(const int* __restrict__ ei, const int* __restrict__ rp,
                       int* __restrict__ fill, int* __restrict__ col) {
  int e = blockIdx.x * 256 + threadIdx.x;
  if (e < EE) {
    int s = ei[e], d = ei[EE + e];
    int pos = atomicAdd(&fill[d], 1);
    col[rp[d] + pos] = s;
  }
}

// ---- GEMM1: h1 = relu(Xb @ W1b^T + b1), written in SLICED layout -----------
// sliced layout: buf[slice][node][16], slice = n>>4 (== nt), within = n&15 (== r)
__global__ __launch_bounds__(256) void k_gemm1(const short* __restrict__ Xb,
                                               const short* __restrict__ W1b,
                                               const float* __restrict__ B1,
                                               short* __restrict__ h1s,
                                               float* __restrict__ st0) {
  int w = threadIdx.x >> 6;
  int lane = threadIdx.x & 63;
  int q = lane >> 4, r = lane & 15;
  int m0 = blockIdx.x * 64 + w * 16;

  f32x4 acc[8];
  #pragma unroll
  for (int i = 0; i < 8; ++i) acc[i] = (f32x4){0.f, 0.f, 0.f, 0.f};

  int row_a = m0 + r;
  if (row_a >= NN) row_a = NN - 1;            // clamp loads, stores masked
  const short* xrow = Xb + (size_t)row_a * DIN + q * 8;

  for (int kc = 0; kc < DIN / 32; ++kc) {
    short8 a = *(const short8*)(xrow + kc * 32);
    #pragma unroll
    for (int nt = 0; nt < 8; ++nt) {
      const short* wrow = W1b + (size_t)(nt * 16 + r) * DIN + q * 8 + kc * 32;
      short8 b = *(const short8*)wrow;
      acc[nt] = __builtin_amdgcn_mfma_f32_16x16x32_bf16(a, b, acc[nt], 0, 0, 0);
    }
  }

  #pragma unroll
  for (int nt = 0; nt < 8; ++nt) {
    float bias = B1[nt * 16 + r];
    #pragma unroll
    for (int reg = 0; reg < 4; ++reg) {
      int row = m0 + q * 4 + reg;             // C/D: row = quad*4 + reg
      if (row < NN) {
        float v = acc[nt][reg] + bias;
        v = v > 0.f ? v : 0.f;
        size_t sidx = (size_t)nt * NN * 16 + (size_t)row * 16 + r;
        h1s[sidx] = f2bf(v);
        st0[sidx] = v;
      }
    }
  }
}

// ---- one APPNP step, x-diffusion + v-diffusion merged into one launch ------
// Sliced state st[slice][node][16], slice = bid&7 -> XCD (round-robin).
// R8 policy (R7 lesson: NEVER nt the loads on the dependence chain):
//   normal loads: col stream (sequential, prefetch-friendly), dinv (200KB,
//                 L2-resident), xc gathers (the reuse set)
//   nt store:  xn (next step's buffer; avoid write-allocate pollution)
//   nt load:   h1 (streamed once, off-chain)
// Edge loop unrolled x8 (was x4): halves the dependent-wait chain depth.
__global__ __launch_bounds__(256) void k_step(const int* __restrict__ rp,
                                              const int* __restrict__ col,
                                              const float* __restrict__ dinv,
                                              const float* __restrict__ xc,
                                              const short* __restrict__ h0,
                                              float* __restrict__ xn,
                                              const float* __restrict__ vc,
                                              float* __restrict__ vn,
                                              int first, int last) {
  if (blockIdx.x >= XSLB) {                   // ---- v-step tail blocks ----
    int i = (blockIdx.x - XSLB) * 256 + threadIdx.x;
    if (i >= NN) return;
    float s = 0.f;
    int e = rp[i], end = rp[i + 1];
    float dii = dinv[i];
    if (first) {                              // vc == 1.0 exactly
      for (; e + 4 <= end; e += 4) {
        int c0 = col[e], c1 = col[e+1], c2 = col[e+2], c3 = col[e+3];
        float v0 = dinv[c0] * dii, v1 = dinv[c1] * dii;
        float v2 = dinv[c2] * dii, v3 = dinv[c3] * dii;
        s += v0; s += v1; s += v2; s += v3;
      }
      for (; e < end; ++e) s += dinv[col[e]] * dii;
      s += dii * dii;
    } else {
      for (; e + 4 <= end; e += 4) {
        int c0 = col[e], c1 = col[e+1], c2 = col[e+2], c3 = col[e+3];
        float v0 = (dinv[c0] * dii) * vc[c0], v1 = (dinv[c1] * dii) * vc[c1];
        float v2 = (dinv[c2] * dii) * vc[c2], v3 = (dinv[c3] * dii) * vc[c3];
        s += v0; s += v1; s += v2; s += v3;
      }
      for (; e < end; ++e) s += (dinv[col[e]] * dii) * vc[col[e]];
      s += dii * dii * vc[i];
    }
    vn[i] = 0.9f * s + 0.1f;
    return;
  }
  // ---- x-step: slice sl for 64 nodes, 4 lanes/node, f32x4/lane ----
  int sl = blockIdx.x & 7;                    // slice -> XCD (round-robin)
  int ck = blockIdx.x >> 3;                   // node chunk
  int node = ck * 64 + (threadIdx.x >> 2);
  if (node >= NN) return;
  int fo = (threadIdx.x & 3) * 4;             // f32 offset within 16-f32 slice
  const float* xsl = xc + (size_t)sl * NN * 16;   // this slice's state base
  int e = rp[node], end = rp[node + 1];
  // hoist independent self-loop + h0 loads off the critical path
  f32x4 xself = *(const f32x4*)(xsl + (size_t)node * 16 + fo);
  ull hq = __builtin_nontemporal_load(
      (const ull*)(h0 + (size_t)sl * NN * 16 + (size_t)node * 16 + fo));
  float di = dinv[node];
  f32x4 acc = (f32x4){0.f, 0.f, 0.f, 0.f};
  for (; e + 8 <= end; e += 8) {
    int s0 = col[e],   s1 = col[e+1], s2 = col[e+2], s3 = col[e+3];
    int s4 = col[e+4], s5 = col[e+5], s6 = col[e+6], s7 = col[e+7];
    float w0 = dinv[s0] * di, w1 = dinv[s1] * di;
    float w2 = dinv[s2] * di, w3 = dinv[s3] * di;
    float w4 = dinv[s4] * di, w5 = dinv[s5] * di;
    float w6 = dinv[s6] * di, w7 = dinv[s7] * di;
    f32x4 x0 = *(const f32x4*)(xsl + (size_t)s0 * 16 + fo);
    f32x4 x1 = *(const f32x4*)(xsl + (size_t)s1 * 16 + fo);
    f32x4 x2 = *(const f32x4*)(xsl + (size_t)s2 * 16 + fo);
    f32x4 x3 = *(const f32x4*)(xsl + (size_t)s3 * 16 + fo);
    f32x4 x4 = *(const f32x4*)(xsl + (size_t)s4 * 16 + fo);
    f32x4 x5 = *(const f32x4*)(xsl + (size_t)s5 * 16 + fo);
    f32x4 x6 = *(const f32x4*)(xsl + (size_t)s6 * 16 + fo);
    f32x4 x7 = *(const f32x4*)(xsl + (size_t)s7 * 16 + fo);
    acc += x0 * w0;                           // sequential: same FP order as
    acc += x1 * w1;                           // the serial loop (bit-exact)
    acc += x2 * w2;
    acc += x3 * w3;
    acc += x4 * w4;
    acc += x5 * w5;
    acc += x6 * w6;
    acc += x7 * w7;
  }
  for (; e + 4 <= end; e += 4) {
    int s0 = col[e], s1 = col[e+1], s2 = col[e+2], s3 = col[e+3];
    float w0 = dinv[s0] * di, w1 = dinv[s1] * di;
    float w2 = dinv[s2] * di, w3 = dinv[s3] * di;
    f32x4 x0 = *(const f32x4*)(xsl + (size_t)s0 * 16 + fo);
    f32x4 x1 = *(const f32x4*)(xsl + (size_t)s1 * 16 + fo);
    f32x4 x2 = *(const f32x4*)(xsl + (size_t)s2 * 16 + fo);
    f32x4 x3 = *(const f32x4*)(xsl + (size_t)s3 * 16 + fo);
    acc += x0 * w0;
    acc += x1 * w1;
    acc += x2 * w2;
    acc += x3 * w3;
  }
  for (; e < end; ++e) {
    int s = col[e];
    acc += *(const f32x4*)(xsl + (size_t)s * 16 + fo) * (dinv[s] * di);
  }
  acc += xself * (di * di);                   // self-loop (original position)
  f32x4 h = { bf2f((short)hq), bf2f((short)(hq >> 16)),
              bf2f((short)(hq >> 32)), bf2f((short)(hq >> 48)) };
  f32x4 res = acc * 0.9f + h * 0.1f;
  if (last) {                                 // out1 is row-major [node][128]
    __builtin_nontemporal_store(res, (f32x4*)(xn + (size_t)node * DH + sl * 16 + fo));
  } else {
    __builtin_nontemporal_store(res, (f32x4*)(xn + (size_t)sl * NN * 16 + (size_t)node * 16 + fo));
  }
}

// ---- GEMM2: out2 = emb1 @ W2^T + v*b2, all f32 -----------------------------
__global__ __launch_bounds__(256) void k_gemm2(const float* __restrict__ emb,
                                               const float* __restrict__ W2,
                                               const float* __restrict__ B2,
                                               const float* __restrict__ v,
                                               float* __restrict__ out2) {
  __shared__ float sW[NC][DH + 1];
  __shared__ float sb[NC];
  __shared__ float sE[32][DH + 1];
  int t = threadIdx.x;
  for (int i = t; i < NC * DH; i += 256) sW[i / DH][i % DH] = W2[i];
  if (t < NC) sb[t] = B2[t];
  int n0 = blockIdx.x * 32;
  for (int i = t; i < 32 * DH; i += 256) {
    int nl = i / DH, kk = i % DH;
    int node = n0 + nl;
    sE[nl][kk] = (node < NN) ? emb[(size_t)node * DH + kk] : 0.f;
  }
  __syncthreads();
  int nl = t >> 3, cb = t & 7;
  int node = n0 + nl;
  if (node >= NN) return;
  float vn = v[node];
  #pragma unroll
  for (int j = 0; j < 8; ++j) {
    int c = cb + 8 * j;
    float s = 0.f;
    #pragma unroll 4
    for (int k = 0; k < DH; ++k) s += sE[nl][k] * sW[c][k];
    s += vn * sb[c];
    out2[(size_t)node * NC + c] = s;
  }
}

extern "C" void kernel_launch(void* const* d_in, const int* in_sizes, int n_in,
                              void* d_out, int out_size, void* d_ws, size_t ws_size,
                              hipStream_t stream) {
  const float* X  = (const float*)d_in[0];   // [50000,512] f32 (102.4MB)
  const int*   EI = (const int*)d_in[1];     // [2,800000] int32
  const float* W1 = (const float*)d_in[2];   // [128,512] f32
  const float* B1 = (const float*)d_in[3];   // [128] f32
  const float* W2 = (const float*)d_in[4];   // [64,128] f32
  const float* B2 = (const float*)d_in[5];   // [64] f32

  // ---- d_out: 35.2M f32 = 140.8MB ----
  float* out0 = (float*)d_out;                    // [0, 102.4MB): x passthrough
  float* out1 = (float*)d_out + 25600000;         // [102.4, 128MB): emb1
  float* out2 = (float*)d_out + 32000000;         // [128, 140.8MB): out

  // ---- scratch in d_in[0]'s 102.4MB region (X consumed first) + d_ws ------
  char* xr = (char*)d_in[0];
  const size_t XB_BYTES = (size_t)NN * DIN * sizeof(short);  // 51.2MB
  bool use_ws = (d_ws != nullptr) && (ws_size >= XB_BYTES);

  float* bufB = (float*)(xr);                 // [0, 25.6MB) f32 (sliced state)
  short* Xb   = use_ws ? (short*)d_ws : (short*)(xr);  // bf16 gemm1 input
  float* bufA = (float*)(xr + 51200000);      // [51.2, 76.8MB) f32 (sliced)
  short* h1   = (short*)(xr + 76800000);      // [76.8, 89.6MB) bf16 (sliced)
  int*   col  = (int*)  (xr + 89600000);      // CSR cols, 3.2MB
  int*   rp   = (int*)  (xr + 96000000);      // 200,004B
  int*   cnt  = (int*)  (xr + 96200192);      // 200,000B
  int*   fill = (int*)  (xr + 96400192);      // 200,000B
  float* dinv = (float*)(xr + 96600192);      // 200,000B
  float* va   = (float*)(xr + 96800192);
  float* vb   = (float*)(xr + 97000192);
  short* W1b  = (short*)(xr + 97200192);      // 128KB
  int*   bsum = (int*)  (xr + 97400192);      // 784B scan block sums

  // X passthrough + bf16 conversion
  if (use_ws) {
    k_copy_conv<<<dim3(25000), dim3(256), 0, stream>>>(
        (const f32x4*)X, (f32x4*)out0, (short4v*)Xb);
  } else {
    k_copy4<<<dim3(25000), dim3(256), 0, stream>>>((const f32x4*)X, (f32x4*)out0);
    k_f2bv <<<dim3(25000), dim3(256), 0, stream>>>(out0, Xb);
  }
  k_f2bv <<<dim3(64), dim3(256), 0, stream>>>(W1, W1b);   // W1 -> bf16

  hipMemsetAsync(cnt, 0, 400000, stream);     // cnt + fill (contiguous)
  k_count<<<dim3(3125), dim3(256), 0, stream>>>(EI, cnt);
  k_scan1<<<dim3(NSB), dim3(256), 0, stream>>>(cnt, rp, bsum, dinv);
  k_scan2<<<dim3(1),   dim3(256), 0, stream>>>(bsum);
  k_scan3<<<dim3(NSB), dim3(256), 0, stream>>>(rp, bsum);
  k_fill <<<dim3(3125), dim3(256), 0, stream>>>(EI, rp, fill, col);

  // h1 (bf16, sliced) + state init (f32, sliced, exact pre-rounding values)
  k_gemm1<<<dim3(782), dim3(256), 0, stream>>>(Xb, W1b, B1, h1, bufA);

  // 10 merged x+v steps; x: A->B, B->A, ... last writes out1 row-major
  for (int it = 0; it < KITER; ++it) {
    const float* xc = (it & 1) ? bufB : bufA;
    float*       xn = (it == KITER - 1) ? out1 : ((it & 1) ? bufA : bufB);
    const float* vcp = (it & 1) ? vb : va;
    float*       vnp = (it & 1) ? va : vb;
    k_step<<<dim3(XSLB + NSB), dim3(256), 0, stream>>>(
        rp, col, dinv, xc, h1, xn, vcp, vnp,
        it == 0 ? 1 : 0, it == KITER - 1 ? 1 : 0);
  }
  // v ends in va (it=9 writes va); emb1 in out1 (row-major)

  // out2 = emb1 @ W2^T + APPNP(1)*b2   (all f32)
  k_gemm2<<<dim3(1563), dim3(256), 0, stream>>>(out1, W2, B2, va, out2);
}

// Round 9
// 1059.505 us; speedup vs baseline: 1.5099x; 1.1907x over previous
//
#include <hip/hip_runtime.h>

#define NN    50000
#define EE    800000
#define DIN   512
#define DH    128
#define NC    64
#define KITER 10
#define NSB   196          // ceil(NN/256) scan blocks; also v-step blocks
#define XSLB  6256         // x-step blocks: 8 slices * 782 node-chunks

typedef __attribute__((ext_vector_type(8))) short short8;
typedef __attribute__((ext_vector_type(4))) short short4v;
typedef __attribute__((ext_vector_type(4))) float f32x4;

static __device__ __forceinline__ float bf2f(short u) {
  unsigned int x = ((unsigned int)(unsigned short)u) << 16;
  return __builtin_bit_cast(float, x);
}
static __device__ __forceinline__ short f2bf(float f) {
  unsigned int x = __builtin_bit_cast(unsigned int, f);
  unsigned int lsb = (x >> 16) & 1u;
  x += 0x7fffu + lsb;                    // round-to-nearest-even
  return (short)(x >> 16);
}

// ---- fused: X -> out0 (byte exact) AND X -> bf16 Xb (in d_ws) --------------
__global__ void k_copy_conv(const f32x4* __restrict__ src, f32x4* __restrict__ dst,
                            short4v* __restrict__ xb) {
  int i = blockIdx.x * 256 + threadIdx.x;       // 6.4M f32x4 exact
  f32x4 s = src[i];
  dst[i] = s;
  short4v o = { f2bf(s.x), f2bf(s.y), f2bf(s.z), f2bf(s.w) };
  xb[i] = o;
}

// ---- fallback pieces (used only if d_ws too small) -------------------------
__global__ void k_copy4(const f32x4* __restrict__ src, f32x4* __restrict__ dst) {
  int i = blockIdx.x * 256 + threadIdx.x;
  dst[i] = src[i];
}

__global__ void k_f2bv(const float* __restrict__ src, short* __restrict__ dst) {
  int j = (blockIdx.x * 256 + threadIdx.x) * 4;
  f32x4 s = *(const f32x4*)(src + j);
  short4v o = { f2bf(s.x), f2bf(s.y), f2bf(s.z), f2bf(s.w) };
  *(short4v*)(dst + j) = o;
}

// ---- CSR build -------------------------------------------------------------
__global__ void k_count(const int* __restrict__ ei, int* __restrict__ cnt) {
  int e = blockIdx.x * 256 + threadIdx.x;
  if (e < EE) atomicAdd(&cnt[ei[EE + e]], 1);
}

// phase 1: per-block inclusive scan + dinv (fused)
__global__ __launch_bounds__(256) void k_scan1(const int* __restrict__ cnt,
                                               int* __restrict__ rp,
                                               int* __restrict__ bsum,
                                               float* __restrict__ dinv) {
  __shared__ int wsum[4];
  int t = threadIdx.x, lane = t & 63, w = t >> 6;
  int i = blockIdx.x * 256 + t;
  int x = (i < NN) ? cnt[i] : 0;
  if (i < NN) dinv[i] = rsqrtf((float)(x + 1));   // +1 self-loop
  #pragma unroll
  for (int off = 1; off < 64; off <<= 1) {
    int y = __shfl_up(x, off);
    if (lane >= off) x += y;
  }
  if (lane == 63) wsum[w] = x;
  __syncthreads();
  int woff = 0;
  #pragma unroll
  for (int j = 0; j < 4; ++j) if (j < w) woff += wsum[j];
  x += woff;
  if (i < NN) rp[i + 1] = x;
  if (t == 255) bsum[blockIdx.x] = x;   // block inclusive total (pad is 0)
}

// phase 2: exclusive scan of the 196 block totals, in place (single block)
__global__ __launch_bounds__(256) void k_scan2(int* __restrict__ bsum) {
  __shared__ int wsum[4];
  int t = threadIdx.x, lane = t & 63, w = t >> 6;
  int orig = (t < NSB) ? bsum[t] : 0;
  int x = orig;
  #pragma unroll
  for (int off = 1; off < 64; off <<= 1) {
    int y = __shfl_up(x, off);
    if (lane >= off) x += y;
  }
  if (lane == 63) wsum[w] = x;
  __syncthreads();
  int woff = 0;
  #pragma unroll
  for (int j = 0; j < 4; ++j) if (j < w) woff += wsum[j];
  x += woff;
  if (t < NSB) bsum[t] = x - orig;      // exclusive prefix
}

// phase 3: add block offsets; rp[0] = 0
__global__ __launch_bounds__(256) void k_scan3(int* __restrict__ rp,
                                               const int* __restrict__ bsum) {
  int i = blockIdx.x * 256 + threadIdx.x;
  if (i == 0) rp[0] = 0;
  if (i < NN) rp[i + 1] += bsum[blockIdx.x];
}

__global__ void k_fill(const int* __restrict__ ei, const int* __restrict__ rp,
                       int* __restrict__ fill, const float* __restrict__ dinv,
                       int* __restrict__ col, float* __restrict__ val) {
  int e = blockIdx.x * 256 + threadIdx.x;
  if (e < EE) {
    int s = ei[e], d = ei[EE + e];
    int pos = atomicAdd(&fill[d], 1);
    int idx = rp[d] + pos;
    col[idx] = s;
    val[idx] = dinv[s] * dinv[d];
  }
}

// ---- GEMM1: h1 = relu(Xb @ W1b^T + b1), written in SLICED layout -----------
// sliced layout: buf[slice][node][16], slice = n>>4 (== nt), within = n&15 (== r)
__global__ __launch_bounds__(256) void k_gemm1(const short* __restrict__ Xb,
                                               const short* __restrict__ W1b,
                                               const float* __restrict__ B1,
                                               short* __restrict__ h1s,
                                               float* __restrict__ st0) {
  int w = threadIdx.x >> 6;
  int lane = threadIdx.x & 63;
  int q = lane >> 4, r = lane & 15;
  int m0 = blockIdx.x * 64 + w * 16;

  f32x4 acc[8];
  #pragma unroll
  for (int i = 0; i < 8; ++i) acc[i] = (f32x4){0.f, 0.f, 0.f, 0.f};

  int row_a = m0 + r;
  if (row_a >= NN) row_a = NN - 1;            // clamp loads, stores masked
  const short* xrow = Xb + (size_t)row_a * DIN + q * 8;

  for (int kc = 0; kc < DIN / 32; ++kc) {
    short8 a = *(const short8*)(xrow + kc * 32);
    #pragma unroll
    for (int nt = 0; nt < 8; ++nt) {
      const short* wrow = W1b + (size_t)(nt * 16 + r) * DIN + q * 8 + kc * 32;
      short8 b = *(const short8*)wrow;
      acc[nt] = __builtin_amdgcn_mfma_f32_16x16x32_bf16(a, b, acc[nt], 0, 0, 0);
    }
  }

  #pragma unroll
  for (int nt = 0; nt < 8; ++nt) {
    float bias = B1[nt * 16 + r];
    #pragma unroll
    for (int reg = 0; reg < 4; ++reg) {
      int row = m0 + q * 4 + reg;             // C/D: row = quad*4 + reg
      if (row < NN) {
        float v = acc[nt][reg] + bias;
        v = v > 0.f ? v : 0.f;
        size_t sidx = (size_t)nt * NN * 16 + (size_t)row * 16 + r;
        h1s[sidx] = f2bf(v);
        st0[sidx] = v;
      }
    }
  }
}

// ---- one APPNP step (R6 known-good form: val array, unroll x4, no nt) ------
__global__ __launch_bounds__(256) void k_step(const int* __restrict__ rp,
                                              const int* __restrict__ col,
                                              const float* __restrict__ val,
                                              const float* __restrict__ dinv,
                                              const float* __restrict__ xc,
                                              const short* __restrict__ h0,
                                              float* __restrict__ xn,
                                              const float* __restrict__ vc,
                                              float* __restrict__ vn,
                                              int first, int last) {
  if (blockIdx.x >= XSLB) {                   // ---- v-step tail blocks ----
    int i = (blockIdx.x - XSLB) * 256 + threadIdx.x;
    if (i >= NN) return;
    float s = 0.f;
    int e = rp[i], end = rp[i + 1];
    if (first) {                              // vc == 1.0 exactly
      for (; e + 4 <= end; e += 4) {
        float v0 = val[e], v1 = val[e+1], v2 = val[e+2], v3 = val[e+3];
        s += v0; s += v1; s += v2; s += v3;
      }
      for (; e < end; ++e) s += val[e];
      float di = dinv[i];
      s += di * di;
    } else {
      for (; e + 4 <= end; e += 4) {
        int c0 = col[e], c1 = col[e+1], c2 = col[e+2], c3 = col[e+3];
        float v0 = val[e]*vc[c0], v1 = val[e+1]*vc[c1];
        float v2 = val[e+2]*vc[c2], v3 = val[e+3]*vc[c3];
        s += v0; s += v1; s += v2; s += v3;
      }
      for (; e < end; ++e) s += val[e] * vc[col[e]];
      float di = dinv[i];
      s += di * di * vc[i];
    }
    vn[i] = 0.9f * s + 0.1f;
    return;
  }
  // ---- x-step: slice sl for 64 nodes, 4 lanes/node, f32x4/lane ----
  int sl = blockIdx.x & 7;                    // slice -> XCD (round-robin)
  int ck = blockIdx.x >> 3;                   // node chunk
  int node = ck * 64 + (threadIdx.x >> 2);
  if (node >= NN) return;
  int fo = (threadIdx.x & 3) * 4;             // f32 offset within 16-f32 slice
  const float* xsl = xc + (size_t)sl * NN * 16;   // this slice's state base
  int e = rp[node], end = rp[node + 1];
  // hoist independent self-loop + h0 loads off the critical path
  f32x4 xself = *(const f32x4*)(xsl + (size_t)node * 16 + fo);
  short4v hv  = *(const short4v*)(h0 + (size_t)sl * NN * 16 + (size_t)node * 16 + fo);
  float di = dinv[node];
  f32x4 acc = (f32x4){0.f, 0.f, 0.f, 0.f};
  for (; e + 4 <= end; e += 4) {
    int s0 = col[e], s1 = col[e+1], s2 = col[e+2], s3 = col[e+3];
    float w0 = val[e], w1 = val[e+1], w2 = val[e+2], w3 = val[e+3];
    f32x4 x0 = *(const f32x4*)(xsl + (size_t)s0 * 16 + fo);
    f32x4 x1 = *(const f32x4*)(xsl + (size_t)s1 * 16 + fo);
    f32x4 x2 = *(const f32x4*)(xsl + (size_t)s2 * 16 + fo);
    f32x4 x3 = *(const f32x4*)(xsl + (size_t)s3 * 16 + fo);
    acc += x0 * w0;                           // sequential: same FP order as
    acc += x1 * w1;                           // the serial loop
    acc += x2 * w2;
    acc += x3 * w3;
  }
  for (; e < end; ++e) {
    acc += *(const f32x4*)(xsl + (size_t)col[e] * 16 + fo) * val[e];
  }
  acc += xself * (di * di);                   // self-loop (original position)
  f32x4 h = { bf2f(hv.x), bf2f(hv.y), bf2f(hv.z), bf2f(hv.w) };
  f32x4 res = acc * 0.9f + h * 0.1f;
  if (last) {                                 // out1 is row-major [node][128]
    *(f32x4*)(xn + (size_t)node * DH + sl * 16 + fo) = res;
  } else {
    *(f32x4*)(xn + (size_t)sl * NN * 16 + (size_t)node * 16 + fo) = res;
  }
}

// ---- GEMM2 (R9 rewrite): 64 nodes/block, 2-node x 8-col register tile, ----
// f32x4 LDS reads. Per-(node,col) k-sum order identical to the old scalar
// loop (sequential k), epilogue identical (+ v*b2) -> bit-exact.
__global__ __launch_bounds__(256) void k_gemm2(const float* __restrict__ emb,
                                               const float* __restrict__ W2,
                                               const float* __restrict__ B2,
                                               const float* __restrict__ v,
                                               float* __restrict__ out2) {
  __shared__ float sW[NC][DH + 4];      // 64 x 132, b128-aligned rows
  __shared__ float sE[64][DH + 4];      // 64 x 132
  __shared__ float sb[NC];
  int t = threadIdx.x;
  // W2: 64x128 = 2048 f32x4, 8 per thread, coalesced
  for (int i = t; i < NC * DH / 4; i += 256) {
    int r = i >> 5, c4 = i & 31;
    *(f32x4*)&sW[r][c4 * 4] = *(const f32x4*)(W2 + r * DH + c4 * 4);
  }
  if (t < NC) sb[t] = B2[t];
  int n0 = blockIdx.x * 64;
  for (int i = t; i < 64 * DH / 4; i += 256) {
    int r = i >> 5, c4 = i & 31;
    int node = n0 + r;
    f32x4 ev = (f32x4){0.f, 0.f, 0.f, 0.f};
    if (node < NN) ev = *(const f32x4*)(emb + (size_t)node * DH + c4 * 4);
    *(f32x4*)&sE[r][c4 * 4] = ev;
  }
  __syncthreads();
  int nl = t >> 3, cb = t & 7;          // nodes nl, nl+32; cols cb+8j
  float acc0[8], acc1[8];
  #pragma unroll
  for (int j = 0; j < 8; ++j) { acc0[j] = 0.f; acc1[j] = 0.f; }
  for (int kk = 0; kk < DH / 4; ++kk) {
    f32x4 e0 = *(const f32x4*)&sE[nl][kk * 4];
    f32x4 e1 = *(const f32x4*)&sE[nl + 32][kk * 4];
    #pragma unroll
    for (int j = 0; j < 8; ++j) {
      f32x4 w = *(const f32x4*)&sW[cb + 8 * j][kk * 4];
      acc0[j] += e0.x * w.x; acc0[j] += e0.y * w.y;   // sequential k order,
      acc0[j] += e0.z * w.z; acc0[j] += e0.w * w.w;   // same as scalar loop
      acc1[j] += e1.x * w.x; acc1[j] += e1.y * w.y;
      acc1[j] += e1.z * w.z; acc1[j] += e1.w * w.w;
    }
  }
  int node0 = n0 + nl, node1 = n0 + nl + 32;
  float v0 = (node0 < NN) ? v[node0] : 0.f;
  float v1 = (node1 < NN) ? v[node1] : 0.f;
  #pragma unroll
  for (int j = 0; j < 8; ++j) {
    int c = cb + 8 * j;
    if (node0 < NN) out2[(size_t)node0 * NC + c] = acc0[j] + v0 * sb[c];
    if (node1 < NN) out2[(size_t)node1 * NC + c] = acc1[j] + v1 * sb[c];
  }
}

extern "C" void kernel_launch(void* const* d_in, const int* in_sizes, int n_in,
                              void* d_out, int out_size, void* d_ws, size_t ws_size,
                              hipStream_t stream) {
  const float* X  = (const float*)d_in[0];   // [50000,512] f32 (102.4MB)
  const int*   EI = (const int*)d_in[1];     // [2,800000] int32
  const float* W1 = (const float*)d_in[2];   // [128,512] f32
  const float* B1 = (const float*)d_in[3];   // [128] f32
  const float* W2 = (const float*)d_in[4];   // [64,128] f32
  const float* B2 = (const float*)d_in[5];   // [64] f32

  // ---- d_out: 35.2M f32 = 140.8MB ----
  float* out0 = (float*)d_out;                    // [0, 102.4MB): x passthrough
  float* out1 = (float*)d_out + 25600000;         // [102.4, 128MB): emb1
  float* out2 = (float*)d_out + 32000000;         // [128, 140.8MB): out

  // ---- scratch in d_in[0]'s 102.4MB region (X consumed first) + d_ws ------
  char* xr = (char*)d_in[0];
  const size_t XB_BYTES = (size_t)NN * DIN * sizeof(short);  // 51.2MB
  bool use_ws = (d_ws != nullptr) && (ws_size >= XB_BYTES);

  float* bufB = (float*)(xr);                 // [0, 25.6MB) f32 (sliced state)
  short* Xb   = use_ws ? (short*)d_ws : (short*)(xr);  // bf16 gemm1 input
  float* bufA = (float*)(xr + 51200000);      // [51.2, 76.8MB) f32 (sliced)
  short* h1   = (short*)(xr + 76800000);      // [76.8, 89.6MB) bf16 (sliced)
  int*   col  = (int*)  (xr + 89600000);      // 3.2MB
  float* val  = (float*)(xr + 92800000);      // 3.2MB
  int*   rp   = (int*)  (xr + 96000000);      // 200,004B
  int*   cnt  = (int*)  (xr + 96200192);      // 200,000B
  int*   fill = (int*)  (xr + 96400192);      // 200,000B
  float* dinv = (float*)(xr + 96600192);      // 200,000B
  float* va   = (float*)(xr + 96800192);
  float* vb   = (float*)(xr + 97000192);
  short* W1b  = (short*)(xr + 97200192);      // 128KB
  int*   bsum = (int*)  (xr + 97400192);      // 784B scan block sums

  // X passthrough + bf16 conversion
  if (use_ws) {
    k_copy_conv<<<dim3(25000), dim3(256), 0, stream>>>(
        (const f32x4*)X, (f32x4*)out0, (short4v*)Xb);
  } else {
    k_copy4<<<dim3(25000), dim3(256), 0, stream>>>((const f32x4*)X, (f32x4*)out0);
    k_f2bv <<<dim3(25000), dim3(256), 0, stream>>>(out0, Xb);
  }
  k_f2bv <<<dim3(64), dim3(256), 0, stream>>>(W1, W1b);   // W1 -> bf16

  hipMemsetAsync(cnt, 0, 400000, stream);     // cnt + fill (contiguous)
  k_count<<<dim3(3125), dim3(256), 0, stream>>>(EI, cnt);
  k_scan1<<<dim3(NSB), dim3(256), 0, stream>>>(cnt, rp, bsum, dinv);
  k_scan2<<<dim3(1),   dim3(256), 0, stream>>>(bsum);
  k_scan3<<<dim3(NSB), dim3(256), 0, stream>>>(rp, bsum);
  k_fill <<<dim3(3125), dim3(256), 0, stream>>>(EI, rp, fill, dinv, col, val);

  // h1 (bf16, sliced) + state init (f32, sliced, exact pre-rounding values)
  k_gemm1<<<dim3(782), dim3(256), 0, stream>>>(Xb, W1b, B1, h1, bufA);

  // 10 merged x+v steps; x: A->B, B->A, ... last writes out1 row-major
  for (int it = 0; it < KITER; ++it) {
    const float* xc = (it & 1) ? bufB : bufA;
    float*       xn = (it == KITER - 1) ? out1 : ((it & 1) ? bufA : bufB);
    const float* vcp = (it & 1) ? vb : va;
    float*       vnp = (it & 1) ? va : vb;
    k_step<<<dim3(XSLB + NSB), dim3(256), 0, stream>>>(
        rp, col, val, dinv, xc, h1, xn, vcp, vnp,
        it == 0 ? 1 : 0, it == KITER - 1 ? 1 : 0);
  }
  // v ends in va (it=9 writes va); emb1 in out1 (row-major)

  // out2 = emb1 @ W2^T + APPNP(1)*b2   (all f32, 64 nodes/block)
  k_gemm2<<<dim3(782), dim3(256), 0, stream>>>(out1, W2, B2, va, out2);
}